// Round 9
// baseline (221.288 us; speedup 1.0000x reference)
//
#include <hip/hip_runtime.h>

// Two-kernel MoE. B=4,S=4096,DIM=2048,BITS=32,HEXP=4 (f32).
// out[t,d] = x[t,d] * ( sum_e v[t,e]*aggr_w[e]*emb[idx[t,e],d] + aggr_b )
// (v,idx) = top4(softmax(x[t]@A1_w.T + A1_b)), descending, ties->lower idx.
//
// K1 router: grid 512 x 512 thr (8 waves), block = 32 tokens, NO LDS in main
//   loop, and sized to FIT 64 VGPRs (the compiler's preferred allocation) so
//   it runs spill-free at 8 waves/SIMD:
//     lane = (t = lane&31 -> token, h = lane>>5 -> 4-dim half of 8-dim chunk)
//     acc[32] = full logit partials for token t over wave's 256-dim slice.
//   Per 8-dim chunk c (32 chunks): 1 x float4/lane; for each k: one W float4
//   (2 distinct addrs/wave = one 32B segment, TA-coalesced, L1/L2-hot since
//   W = 256KB) feeding 4 FMAs/lane. 8 waves/SIMD hide the W-load latency.
//   Epilogue: shfl_xor(32) h-combine -> red[8][32][36] -> softmax/top4
//   (1 thread/token, ties->lower) -> gates to d_ws.
// K2 combine: verbatim from the 98.9us round.

#define NTOK 16384
#define DIMV 2048

__global__ __launch_bounds__(512, 4) void router_k(
    const float* __restrict__ x,
    const float* __restrict__ A1w,
    const float* __restrict__ A1b,
    const float* __restrict__ aggw,
    float* __restrict__ gates)
{
    __shared__ float smem[9216];               // red[8][32][36] only (36KB)

    const int tid  = threadIdx.x;
    const int lane = tid & 63;
    const int wid  = tid >> 6;
    const int t    = lane & 31;                // token
    const int h    = lane >> 5;                // 4-dim half within 8-dim chunk
    const int tok0 = blockIdx.x << 5;          // 32 tokens/block
    const int dbase = (wid << 8) + (h << 2);   // wave slice + half offset

    const float* xrow  = x   + (size_t)(tok0 + t) * DIMV + dbase;
    const float* wbase = A1w + dbase;

    float acc[32];
    #pragma unroll
    for (int k = 0; k < 32; ++k) acc[k] = 0.f;

    float4 xv = *(const float4*)(xrow);

    for (int c = 0; c < 32; ++c) {             // 32 chunks x 8 dims
        const int cn = (c < 31) ? (c + 1) : 31;
        const float4 xn = *(const float4*)(xrow + (cn << 3));   // next chunk
        const float* wc = wbase + (c << 3);
        #pragma unroll
        for (int k = 0; k < 32; ++k) {
            const float4 w = *(const float4*)(wc + k * DIMV);
            float a = acc[k];
            a = fmaf(xv.x, w.x, a); a = fmaf(xv.y, w.y, a);
            a = fmaf(xv.z, w.z, a); a = fmaf(xv.w, w.w, a);
            acc[k] = a;
        }
        xv = xn;
    }

    // combine dim-halves: lane t (h=0) + lane t+32 (h=1) hold same token
    #pragma unroll
    for (int k = 0; k < 32; ++k) acc[k] += __shfl_xor(acc[k], 32);

    float* red = smem;                          // red[8][32][36]
    if (lane < 32) {
        float* r = red + wid * 1152 + t * 36;
        #pragma unroll
        for (int q = 0; q < 8; ++q)
            *(float4*)&r[q << 2] = make_float4(acc[4*q], acc[4*q+1],
                                               acc[4*q+2], acc[4*q+3]);
    }
    __syncthreads();

    // softmax + top4 + gates: one thread per token (32 of 512)
    if (tid < 32) {
        const int tt = tid;
        float l[32];
        #pragma unroll
        for (int q = 0; q < 8; ++q) {
            float4 v = make_float4(0.f, 0.f, 0.f, 0.f);
            #pragma unroll
            for (int w = 0; w < 8; ++w) {
                const float4 p = *(const float4*)&red[w * 1152 + tt * 36 + (q << 2)];
                v.x += p.x; v.y += p.y; v.z += p.z; v.w += p.w;
            }
            l[4*q]   = v.x + A1b[4*q];
            l[4*q+1] = v.y + A1b[4*q+1];
            l[4*q+2] = v.z + A1b[4*q+2];
            l[4*q+3] = v.w + A1b[4*q+3];
        }
        float m = l[0];
        #pragma unroll
        for (int k = 1; k < 32; ++k) m = fmaxf(m, l[k]);
        float s = 0.f;
        #pragma unroll
        for (int k = 0; k < 32; ++k) { l[k] = expf(l[k] - m); s += l[k]; }
        const float inv = 1.0f / s;

        unsigned used = 0u;
        float gv[4]; unsigned iv[4];
        #pragma unroll
        for (int e = 0; e < 4; ++e) {
            float best = -1.f; int bi = 0;
            #pragma unroll
            for (int k = 0; k < 32; ++k) {
                bool ok = !((used >> k) & 1u) && (l[k] > best);
                best = ok ? l[k] : best;
                bi   = ok ? k    : bi;
            }
            used |= (1u << bi);
            gv[e] = best * inv * aggw[e];       // gate * aggr_w[e]
            iv[e] = (unsigned)bi;
        }
        float* gp = gates + (size_t)(tok0 + tt) * 8;
        *(float4*)gp = make_float4(gv[0], gv[1], gv[2], gv[3]);
        *(float4*)(gp + 4) = make_float4(__uint_as_float(iv[0]), __uint_as_float(iv[1]),
                                         __uint_as_float(iv[2]), __uint_as_float(iv[3]));
    }
}

// K2: gather + combine + residual (verbatim from the 98.9us round).
__global__ __launch_bounds__(256) void moe_out_k(
    const float* __restrict__ x,
    const float* __restrict__ emb,
    const float* __restrict__ gates,
    const float* __restrict__ aggb,
    float* __restrict__ out)
{
    const int t   = blockIdx.x;
    const int tid = threadIdx.x;
    const float* gp = gates + (size_t)t * 8;
    const float4 g  = *(const float4*)gp;
    const float4 ibits = *(const float4*)(gp + 4);
    const unsigned i0 = __float_as_uint(ibits.x);
    const unsigned i1 = __float_as_uint(ibits.y);
    const unsigned i2 = __float_as_uint(ibits.z);
    const unsigned i3 = __float_as_uint(ibits.w);
    const float b = aggb[0];
    const size_t base = (size_t)t * DIMV;

    #pragma unroll
    for (int h = 0; h < DIMV; h += 1024) {
        const int d = h + (tid << 2);
        const float4 xv = *(const float4*)&x[base + d];
        const float4 e0 = *(const float4*)&emb[(size_t)i0 * DIMV + d];
        const float4 e1 = *(const float4*)&emb[(size_t)i1 * DIMV + d];
        const float4 e2 = *(const float4*)&emb[(size_t)i2 * DIMV + d];
        const float4 e3 = *(const float4*)&emb[(size_t)i3 * DIMV + d];
        float4 a, o;
        a.x = fmaf(g.x, e0.x, fmaf(g.y, e1.x, fmaf(g.z, e2.x, fmaf(g.w, e3.x, b))));
        a.y = fmaf(g.x, e0.y, fmaf(g.y, e1.y, fmaf(g.z, e2.y, fmaf(g.w, e3.y, b))));
        a.z = fmaf(g.x, e0.z, fmaf(g.y, e1.z, fmaf(g.z, e2.z, fmaf(g.w, e3.z, b))));
        a.w = fmaf(g.x, e0.w, fmaf(g.y, e1.w, fmaf(g.z, e2.w, fmaf(g.w, e3.w, b))));
        o.x = xv.x * a.x; o.y = xv.y * a.y; o.z = xv.z * a.z; o.w = xv.w * a.w;
        *(float4*)&out[base + d] = o;
    }
}

extern "C" void kernel_launch(void* const* d_in, const int* in_sizes, int n_in,
                              void* d_out, int out_size, void* d_ws, size_t ws_size,
                              hipStream_t stream)
{
    (void)in_sizes; (void)n_in; (void)out_size; (void)ws_size;
    const float* x    = (const float*)d_in[0];
    const float* A1w  = (const float*)d_in[1];
    const float* A1b  = (const float*)d_in[2];
    const float* emb  = (const float*)d_in[3];
    const float* aggw = (const float*)d_in[4];
    const float* aggb = (const float*)d_in[5];
    float* out   = (float*)d_out;
    float* gates = (float*)d_ws;               // 16384 * 8 f32 = 512 KB

    router_k<<<NTOK / 32, 512, 0, stream>>>(x, A1w, A1b, aggw, gates);
    moe_out_k<<<NTOK, 256, 0, stream>>>(x, emb, gates, aggb, out);
}

// Round 10
// 191.932 us; speedup vs baseline: 1.1530x; 1.1530x over previous
//
#include <hip/hip_runtime.h>

// Two-kernel MoE. B=4,S=4096,DIM=2048,BITS=32,HEXP=4 (f32).
// out[t,d] = x[t,d] * ( sum_e v[t,e]*aggr_w[e]*emb[idx[t,e],d] + aggr_b )
// (v,idx) = top4(softmax(x[t]@A1_w.T + A1_b)), descending, ties->lower idx.
//
// K1 router: grid 512 x 512 thr (8 waves), block = 32 tokens, no LDS in the
//   main loop, and sized to fit 64 ARCH VGPRs so the compiler neither spills
//   nor demotes accumulators to AGPRs (R8/R9 lesson: acc[32+] under an
//   occupancy bound -> v_accvgpr_read/write per FMA = 3x VALU):
//     wave wid = (kh = wid&1 -> 16 bits, q = wid>>1 -> 512-dim quarter)
//     lane     = (t = lane&31 -> token, h = lane>>5 -> 8-dim half of chunk)
//     acc[16]  = token t's partials for the wave's 16 bits over its dims.
//   Per 16-dim chunk: x = 2 dwordx4/lane; per bit kk: W = 2 dwordx4/lane
//   (t-lanes share the address -> 2 lines/wave-instr, W 256KB L1/L2-hot),
//   8 FMA. 4 FMA per W-load with ~3-deep compiler prefetch in spare regs.
//   Epilogue: shfl_xor(32) h-combine -> red[4][32][36] (kh-waves write
//   their 16-k half-row) -> softmax/top4 (1 thr/token) -> gates to d_ws.
// K2 combine: verbatim from the 98.9us round.

#define NTOK 16384
#define DIMV 2048

__global__ __launch_bounds__(512, 4) void router_k(
    const float* __restrict__ x,
    const float* __restrict__ A1w,
    const float* __restrict__ A1b,
    const float* __restrict__ aggw,
    float* __restrict__ gates)
{
    __shared__ float smem[4608];               // red[4][32][36] (18KB)

    const int tid  = threadIdx.x;
    const int lane = tid & 63;
    const int wid  = tid >> 6;
    const int kh   = wid & 1;                  // 16-bit half: bits [16kh,16kh+16)
    const int q    = wid >> 1;                 // dim quarter [512q, 512q+512)
    const int t    = lane & 31;                // token
    const int h    = lane >> 5;                // 8-dim half within 16-dim chunk
    const int tok0 = blockIdx.x << 5;          // 32 tokens/block
    const int dbase = (q << 9) + (h << 3);     // quarter + half offset

    const float* xrow  = x   + (size_t)(tok0 + t) * DIMV + dbase;
    const float* wbase = A1w + (size_t)(kh << 4) * DIMV + dbase;

    float acc[16];
    #pragma unroll
    for (int k = 0; k < 16; ++k) acc[k] = 0.f;

    float4 xa = *(const float4*)(xrow);
    float4 xb = *(const float4*)(xrow + 4);

    for (int c = 0; c < 32; ++c) {             // 32 chunks x 16 dims = 512
        const int cn = (c < 31) ? (c + 1) : 31;
        const float4 xna = *(const float4*)(xrow + (cn << 4));
        const float4 xnb = *(const float4*)(xrow + (cn << 4) + 4);
        const float* wc = wbase + (c << 4);
        #pragma unroll
        for (int kk = 0; kk < 16; ++kk) {
            const float4 w0 = *(const float4*)(wc + (size_t)kk * DIMV);
            const float4 w1 = *(const float4*)(wc + (size_t)kk * DIMV + 4);
            float a = acc[kk];
            a = fmaf(xa.x, w0.x, a); a = fmaf(xa.y, w0.y, a);
            a = fmaf(xa.z, w0.z, a); a = fmaf(xa.w, w0.w, a);
            a = fmaf(xb.x, w1.x, a); a = fmaf(xb.y, w1.y, a);
            a = fmaf(xb.z, w1.z, a); a = fmaf(xb.w, w1.w, a);
            acc[kk] = a;
        }
        xa = xna; xb = xnb;
    }

    // combine dim-halves: lane t and lane t+32 hold the same (token, kh, q)
    #pragma unroll
    for (int k = 0; k < 16; ++k) acc[k] += __shfl_xor(acc[k], 32);

    // red[q][t][kh*16 + kk]: each (kh,q) wave writes its 16-k half-row
    float* red = smem;
    if (lane < 32) {
        float* r = red + q * 1152 + t * 36 + (kh << 4);
        #pragma unroll
        for (int j = 0; j < 4; ++j)
            *(float4*)&r[j << 2] = make_float4(acc[4*j], acc[4*j+1],
                                               acc[4*j+2], acc[4*j+3]);
    }
    __syncthreads();

    // softmax + top4 + gates: one thread per token (32 of 512)
    if (tid < 32) {
        const int tt = tid;
        float l[32];
        #pragma unroll
        for (int j = 0; j < 8; ++j) {
            float4 v = make_float4(0.f, 0.f, 0.f, 0.f);
            #pragma unroll
            for (int qq = 0; qq < 4; ++qq) {
                const float4 p = *(const float4*)&red[qq * 1152 + tt * 36 + (j << 2)];
                v.x += p.x; v.y += p.y; v.z += p.z; v.w += p.w;
            }
            l[4*j]   = v.x + A1b[4*j];
            l[4*j+1] = v.y + A1b[4*j+1];
            l[4*j+2] = v.z + A1b[4*j+2];
            l[4*j+3] = v.w + A1b[4*j+3];
        }
        float m = l[0];
        #pragma unroll
        for (int k = 1; k < 32; ++k) m = fmaxf(m, l[k]);
        float s = 0.f;
        #pragma unroll
        for (int k = 0; k < 32; ++k) { l[k] = expf(l[k] - m); s += l[k]; }
        const float inv = 1.0f / s;

        unsigned used = 0u;
        float gv[4]; unsigned iv[4];
        #pragma unroll
        for (int e = 0; e < 4; ++e) {
            float best = -1.f; int bi = 0;
            #pragma unroll
            for (int k = 0; k < 32; ++k) {
                bool ok = !((used >> k) & 1u) && (l[k] > best);
                best = ok ? l[k] : best;
                bi   = ok ? k    : bi;
            }
            used |= (1u << bi);
            gv[e] = best * inv * aggw[e];       // gate * aggr_w[e]
            iv[e] = (unsigned)bi;
        }
        float* gp = gates + (size_t)(tok0 + tt) * 8;
        *(float4*)gp = make_float4(gv[0], gv[1], gv[2], gv[3]);
        *(float4*)(gp + 4) = make_float4(__uint_as_float(iv[0]), __uint_as_float(iv[1]),
                                         __uint_as_float(iv[2]), __uint_as_float(iv[3]));
    }
}

// K2: gather + combine + residual (verbatim from the 98.9us round).
__global__ __launch_bounds__(256) void moe_out_k(
    const float* __restrict__ x,
    const float* __restrict__ emb,
    const float* __restrict__ gates,
    const float* __restrict__ aggb,
    float* __restrict__ out)
{
    const int t   = blockIdx.x;
    const int tid = threadIdx.x;
    const float* gp = gates + (size_t)t * 8;
    const float4 g  = *(const float4*)gp;
    const float4 ibits = *(const float4*)(gp + 4);
    const unsigned i0 = __float_as_uint(ibits.x);
    const unsigned i1 = __float_as_uint(ibits.y);
    const unsigned i2 = __float_as_uint(ibits.z);
    const unsigned i3 = __float_as_uint(ibits.w);
    const float b = aggb[0];
    const size_t base = (size_t)t * DIMV;

    #pragma unroll
    for (int h = 0; h < DIMV; h += 1024) {
        const int d = h + (tid << 2);
        const float4 xv = *(const float4*)&x[base + d];
        const float4 e0 = *(const float4*)&emb[(size_t)i0 * DIMV + d];
        const float4 e1 = *(const float4*)&emb[(size_t)i1 * DIMV + d];
        const float4 e2 = *(const float4*)&emb[(size_t)i2 * DIMV + d];
        const float4 e3 = *(const float4*)&emb[(size_t)i3 * DIMV + d];
        float4 a, o;
        a.x = fmaf(g.x, e0.x, fmaf(g.y, e1.x, fmaf(g.z, e2.x, fmaf(g.w, e3.x, b))));
        a.y = fmaf(g.x, e0.y, fmaf(g.y, e1.y, fmaf(g.z, e2.y, fmaf(g.w, e3.y, b))));
        a.z = fmaf(g.x, e0.z, fmaf(g.y, e1.z, fmaf(g.z, e2.z, fmaf(g.w, e3.z, b))));
        a.w = fmaf(g.x, e0.w, fmaf(g.y, e1.w, fmaf(g.z, e2.w, fmaf(g.w, e3.w, b))));
        o.x = xv.x * a.x; o.y = xv.y * a.y; o.z = xv.z * a.z; o.w = xv.w * a.w;
        *(float4*)&out[base + d] = o;
    }
}

extern "C" void kernel_launch(void* const* d_in, const int* in_sizes, int n_in,
                              void* d_out, int out_size, void* d_ws, size_t ws_size,
                              hipStream_t stream)
{
    (void)in_sizes; (void)n_in; (void)out_size; (void)ws_size;
    const float* x    = (const float*)d_in[0];
    const float* A1w  = (const float*)d_in[1];
    const float* A1b  = (const float*)d_in[2];
    const float* emb  = (const float*)d_in[3];
    const float* aggw = (const float*)d_in[4];
    const float* aggb = (const float*)d_in[5];
    float* out   = (float*)d_out;
    float* gates = (float*)d_ws;               // 16384 * 8 f32 = 512 KB

    router_k<<<NTOK / 32, 512, 0, stream>>>(x, A1w, A1b, aggw, gates);
    moe_out_k<<<NTOK, 256, 0, stream>>>(x, emb, gates, aggb, out);
}